// Round 23
// baseline (390.918 us; speedup 1.0000x reference)
//
#include <hip/hip_runtime.h>
#include <math.h>

#define B_SZ 4096
#define N_SZ 200
#define K_SZ 64
#define H1 80
#define H2 40
#define NEG_V (-4294967295.0f)

#define W1ELT 5120               // layer-1 W_eff frag image elements
#define W2HALVES 4608            // layer-2 frag image halves
#define WLDS_HALVES (W1ELT + W2HALVES)  // 9728 halves = 19,456 B
#define BPB 4                    // batch rows per block

typedef _Float16 f16x8 __attribute__((ext_vector_type(8)));
typedef float f32x4 __attribute__((ext_vector_type(4)));
typedef unsigned int u32;

union H2U { _Float16 h[2]; u32 u; };
union U4F { u32 u[4]; f16x8 v; };

typedef __attribute__((address_space(3))) u32 lds_u32;
typedef const __attribute__((address_space(1))) u32 glb_u32;

__device__ __forceinline__ void gload16(const void* gp, void* lp) {
    __builtin_amdgcn_global_load_lds((glb_u32*)gp, (lds_u32*)lp, 16, 0, 0);
}

// ---------------- qW[b][h] = b1[h] + sum_i q[b][i]*(W1[i][h]+W1[128+i][h])  (exact fp32)
__global__ __launch_bounds__(128) void qw_kernel(const float* __restrict__ query,
                                                 const float* __restrict__ W1,
                                                 const float* __restrict__ b1,
                                                 float* __restrict__ qW) {
    int b = blockIdx.x;
    int tid = threadIdx.x;
    __shared__ float sq[K_SZ];
    if (tid < K_SZ) sq[tid] = query[b * K_SZ + tid];
    __syncthreads();
    if (tid < H1) {
        float acc = b1[tid];
#pragma unroll 8
        for (int i = 0; i < K_SZ; ++i)
            acc += sq[i] * (W1[i * H1 + tid] + W1[(128 + i) * H1 + tid]);
        qW[b * H1 + tid] = acc;
    }
}

// ---------------- pack weights (layouts as R18/R21)
__global__ __launch_bounds__(256) void prep_bp(const float* __restrict__ W1,
                                               const float* __restrict__ W2,
                                               float* __restrict__ W1kG,
                                               float* __restrict__ W1pG,
                                               _Float16* __restrict__ Bp2) {
    int idx = blockIdx.x * 256 + threadIdx.x;
    if (idx < W1ELT) {
        int j = idx & 7, lane = (idx >> 3) & 63, f = idx >> 9;
        int ks = f & 1, ht = f >> 1;
        int k = ks * 32 + (lane >> 4) * 8 + j;
        int h = ht * 16 + (lane & 15);
        W1kG[idx] = W1[(64 + k) * H1 + h] - W1[(128 + k) * H1 + h];
        W1pG[idx] = W1[(192 + k) * H1 + h];
    } else {
        int idx2 = idx - W1ELT;
        if (idx2 < W2HALVES) {
            int j = idx2 & 7, lane = (idx2 >> 3) & 63, f2 = idx2 >> 9;
            int ks2 = f2 % 3, ht2 = f2 / 3;
            int k2 = ks2 * 32 + (lane >> 4) * 8 + j;
            int m = ht2 * 16 + (lane & 15);
            float w = (k2 < H1 && m < H2) ? W2[k2 * H2 + m] : 0.0f;
            Bp2[idx2] = (_Float16)w;
        }
    }
}

__device__ __forceinline__ void load_keys(const float* __restrict__ key,
                                          const float* __restrict__ /*unused*/,
                                          int p0, int tb, int NT, int l15, int lg,
                                          f16x8 Bk[4][2]) {
#pragma unroll
    for (int i = 0; i < 4; ++i) {
        if (i < NT) {
            int nloc = (tb + i) * 16 + l15;
            int pg = p0 + nloc;
            int pgc = (pg < B_SZ * N_SZ) ? pg : (B_SZ * N_SZ - 1);
#pragma unroll
            for (int ksp = 0; ksp < 2; ++ksp) {
                const float* kp = &key[(size_t)pgc * K_SZ + ksp * 32 + lg * 8];
                float4 k0 = *reinterpret_cast<const float4*>(kp);
                float4 k1 = *reinterpret_cast<const float4*>(kp + 4);
                f16x8 bk;
                bk[0] = (_Float16)k0.x; bk[1] = (_Float16)k0.y; bk[2] = (_Float16)k0.z; bk[3] = (_Float16)k0.w;
                bk[4] = (_Float16)k1.x; bk[5] = (_Float16)k1.y; bk[6] = (_Float16)k1.z; bk[7] = (_Float16)k1.w;
                Bk[i][ksp] = bk;
            }
        }
    }
}

// ---------------- fused, 4 b's per block with cross-b key prefetch pipeline.
__global__ __launch_bounds__(256, 3) void fused_kernel(
    const float* __restrict__ query, const float* __restrict__ key,
    const float* __restrict__ value, const int* __restrict__ mask,
    const float* __restrict__ W1kG, const float* __restrict__ W1pG,
    const _Float16* __restrict__ Bp2G,
    const float* __restrict__ a1, const float* __restrict__ b2,
    const float* __restrict__ a2, const float* __restrict__ Wo,
    const float* __restrict__ bo, const float* __restrict__ qW,
    float* __restrict__ out) {
    __shared__ _Float16 wlds[WLDS_HALVES];   // [0,5120): W_eff  [5120,9728): W2
    __shared__ float sq[K_SZ];
    __shared__ float sqW[H1];
    __shared__ float sa1[H1];
    __shared__ float sb2[48], sa2[48], sWo[48];
    __shared__ float sprob[256];
    __shared__ float sred[8];
    __shared__ float spart[4 * K_SZ];

    const int tid = threadIdx.x;
    const int wv = tid >> 6;
    const int l = tid & 63;
    const int l15 = l & 15;
    const int lg = l >> 4;
    const int bb0 = blockIdx.x * BPB;
    const int NT = (wv == 0) ? 4 : 3;
    const int tb = (wv == 0) ? 0 : 1 + wv * 3;

    // ---- once per block: W2 frag DMA + static params
    {
#pragma unroll
        for (int i = 0; i < 2; ++i) {
            int cb = i * 256 + wv * 64;
            gload16(&Bp2G[(size_t)(cb + l) * 8], (char*)&wlds[W1ELT] + (size_t)cb * 16);
        }
        if (wv == 0) {
            int cb = 512;
            gload16(&Bp2G[(size_t)(cb + l) * 8], (char*)&wlds[W1ELT] + (size_t)cb * 16);
        }
    }
    if (tid < H1) sa1[tid] = a1[tid];
    if (tid >= 128 && tid < 176) {
        int i = tid - 128;
        sb2[i] = (i < H2) ? b2[i] : 0.0f;
        sa2[i] = (i < H2) ? a2[i] : 0.0f;
        sWo[i] = (i < H2) ? Wo[i] : 0.0f;
    }
    float bov = bo[0];

    const int wofs = l * 8;

    // prologue: keys for first b
    f16x8 Bkb[2][4][2];
    load_keys(key, nullptr, bb0 * N_SZ, tb, NT, l15, lg, Bkb[0]);

#pragma unroll
    for (int it = 0; it < BPB; ++it) {
        const int b = bb0 + it;
        const int p0 = b * N_SZ;

        // ---- stage per-b params
        if (tid < K_SZ) sq[tid] = query[(size_t)b * K_SZ + tid];
        if (tid < H1) sqW[tid] = qW[(size_t)b * H1 + tid];
        __syncthreads();   // B0: sq/sqW visible (it==0 also drains W2 DMA)

        // ---- W_eff fold (fp32 combine, one fp16 round)
#pragma unroll
        for (int r = 0; r < 20; ++r) {
            int idx = r * 256 + tid;
            int j = idx & 7, lane = (idx >> 3) & 63, f = idx >> 9;
            int k = (f & 1) * 32 + ((lane >> 4) * 8) + j;
            float w = W1kG[idx] + sq[k] * W1pG[idx];
            wlds[idx] = (_Float16)w;
        }
        __syncthreads();   // B1: W_eff visible

        // ---- layer 1
        f32x4 D1[4][5];
#pragma unroll
        for (int i = 0; i < 4; ++i)
#pragma unroll
            for (int ht = 0; ht < 5; ++ht) D1[i][ht] = (f32x4){0.f, 0.f, 0.f, 0.f};
#pragma unroll
        for (int ht = 0; ht < 5; ++ht) {
#pragma unroll
            for (int ks = 0; ks < 2; ++ks) {
                f16x8 wh = *reinterpret_cast<const f16x8*>(&wlds[(ht * 2 + ks) * 512 + wofs]);
#pragma unroll
                for (int i = 0; i < 4; ++i) {
                    if (i < NT) {
                        D1[i][ht] = __builtin_amdgcn_mfma_f32_16x16x32_f16(
                            wh, Bkb[it & 1][i][ks], D1[i][ht], 0, 0, 0);
                    }
                }
            }
        }

        // ---- prefetch next-b keys (retire under epilogue/layer2/softmax)
        if (it < BPB - 1) {
            load_keys(key, nullptr, (b + 1) * N_SZ, tb, NT, l15, lg, Bkb[(it + 1) & 1]);
        }

        // ---- epilogue 1: h1 = prelu(D1 + qW) -> packed fp16 pairs
        u32 pk[4][6][2];
#pragma unroll
        for (int i = 0; i < 4; ++i) {
            if (i < NT) {
#pragma unroll
                for (int ht = 0; ht < 5; ++ht) {
                    float4 qw4 = *reinterpret_cast<const float4*>(&sqW[ht * 16 + lg * 4]);
                    float4 aa4 = *reinterpret_cast<const float4*>(&sa1[ht * 16 + lg * 4]);
                    float h0 = D1[i][ht][0] + qw4.x;
                    float h1v = D1[i][ht][1] + qw4.y;
                    float h2 = D1[i][ht][2] + qw4.z;
                    float h3 = D1[i][ht][3] + qw4.w;
                    h0 = (h0 > 0.f) ? h0 : h0 * aa4.x;
                    h1v = (h1v > 0.f) ? h1v : h1v * aa4.y;
                    h2 = (h2 > 0.f) ? h2 : h2 * aa4.z;
                    h3 = (h3 > 0.f) ? h3 : h3 * aa4.w;
                    H2U u0, u1;
                    u0.h[0] = (_Float16)h0; u0.h[1] = (_Float16)h1v;
                    u1.h[0] = (_Float16)h2; u1.h[1] = (_Float16)h3;
                    pk[i][ht][0] = u0.u;
                    pk[i][ht][1] = u1.u;
                }
                pk[i][5][0] = 0u; pk[i][5][1] = 0u;
            }
        }

        // ---- layer 2
        f32x4 D2[4][3];
#pragma unroll
        for (int i = 0; i < 4; ++i)
#pragma unroll
            for (int ht = 0; ht < 3; ++ht) D2[i][ht] = (f32x4){0.f, 0.f, 0.f, 0.f};
#pragma unroll
        for (int ks2 = 0; ks2 < 3; ++ks2) {
            f16x8 B2f[4];
#pragma unroll
            for (int i = 0; i < 4; ++i) {
                if (i < NT) {
                    U4F bu;
#pragma unroll
                    for (int q = 0; q < 4; ++q) {
                        int src = ((lg * 2 + (q >> 1)) & 3) * 16 + l15;
                        u32 va = (u32)__shfl((int)pk[i][ks2 * 2][q & 1], src, 64);
                        u32 vb = (u32)__shfl((int)pk[i][ks2 * 2 + 1][q & 1], src, 64);
                        bu.u[q] = (lg < 2) ? va : vb;
                    }
                    B2f[i] = bu.v;
                }
            }
#pragma unroll
            for (int ht2 = 0; ht2 < 3; ++ht2) {
                f16x8 wh = *reinterpret_cast<const f16x8*>(&wlds[W1ELT + (ht2 * 3 + ks2) * 512 + wofs]);
#pragma unroll
                for (int i = 0; i < 4; ++i) {
                    if (i < NT) {
                        D2[i][ht2] = __builtin_amdgcn_mfma_f32_16x16x32_f16(wh, B2f[i], D2[i][ht2], 0, 0, 0);
                    }
                }
            }
        }

        // ---- epilogue 2 + layer 3
#pragma unroll
        for (int i = 0; i < 4; ++i) {
            if (i < NT) {
                float psum = 0.f;
#pragma unroll
                for (int ht2 = 0; ht2 < 3; ++ht2) {
                    float4 b4 = *reinterpret_cast<const float4*>(&sb2[ht2 * 16 + lg * 4]);
                    float4 a4 = *reinterpret_cast<const float4*>(&sa2[ht2 * 16 + lg * 4]);
                    float4 w4 = *reinterpret_cast<const float4*>(&sWo[ht2 * 16 + lg * 4]);
                    float v0 = D2[i][ht2][0] + b4.x;
                    float v1 = D2[i][ht2][1] + b4.y;
                    float v2 = D2[i][ht2][2] + b4.z;
                    float v3 = D2[i][ht2][3] + b4.w;
                    v0 = (v0 > 0.f) ? v0 : v0 * a4.x;
                    v1 = (v1 > 0.f) ? v1 : v1 * a4.y;
                    v2 = (v2 > 0.f) ? v2 : v2 * a4.z;
                    v3 = (v3 > 0.f) ? v3 : v3 * a4.w;
                    psum += v0 * w4.x + v1 * w4.y + v2 * w4.z + v3 * w4.w;
                }
                psum += __shfl_xor(psum, 16);
                psum += __shfl_xor(psum, 32);
                if (lg == 0) {
                    int nloc = (tb + i) * 16 + l15;
                    float sv;
                    if (nloc < N_SZ) sv = (mask[p0 + nloc] == 0) ? NEG_V : (psum + bov);
                    else sv = -INFINITY;
                    sprob[nloc] = sv;
                }
            }
        }
        __syncthreads();   // B2: scores staged

        // ---- softmax over 208 (pads -inf)
        float s = (tid < 208) ? sprob[tid] : -INFINITY;
        float m = s;
#pragma unroll
        for (int off = 32; off >= 1; off >>= 1) m = fmaxf(m, __shfl_xor(m, off));
        if ((tid & 63) == 0) sred[tid >> 6] = m;
        __syncthreads();   // B3
        m = fmaxf(fmaxf(sred[0], sred[1]), fmaxf(sred[2], sred[3]));

        float e = (tid < 208) ? expf(s - m) : 0.0f;
        sprob[tid] = e;
        float t = e;
#pragma unroll
        for (int off = 32; off >= 1; off >>= 1) t += __shfl_xor(t, off);
        if ((tid & 63) == 0) sred[4 + (tid >> 6)] = t;
        __syncthreads();   // B4
        float inv = 1.0f / (sred[4] + sred[5] + sred[6] + sred[7]);

        // ---- value tail (R21 form: float4, issued at use, deep)
        {
            const int n0 = wv * 50;
            const int kc = l15 * 4;
            float4 vr[13];
#pragma unroll
            for (int q = 0; q < 13; ++q) {
                int sub = q * 4 + lg;
                int row = n0 + ((sub < 50) ? sub : 49);
                vr[q] = *reinterpret_cast<const float4*>(
                    &value[((size_t)p0 + row) * K_SZ + kc]);
            }
            f32x4 vacc = (f32x4){0.f, 0.f, 0.f, 0.f};
#pragma unroll
            for (int q = 0; q < 13; ++q) {
                int sub = q * 4 + lg;
                float w = (sub < 50) ? sprob[n0 + sub] : 0.0f;
                vacc[0] += w * vr[q].x;
                vacc[1] += w * vr[q].y;
                vacc[2] += w * vr[q].z;
                vacc[3] += w * vr[q].w;
            }
#pragma unroll
            for (int e2 = 0; e2 < 4; ++e2) {
                vacc[e2] += __shfl_xor(vacc[e2], 16);
                vacc[e2] += __shfl_xor(vacc[e2], 32);
            }
            if (lg == 0) {
                float4 vout = {vacc[0], vacc[1], vacc[2], vacc[3]};
                *reinterpret_cast<float4*>(&spart[wv * K_SZ + kc]) = vout;
            }
        }
        __syncthreads();   // B5: spart complete
        if (tid < K_SZ) {
            out[(size_t)b * K_SZ + tid] =
                (spart[tid] + spart[64 + tid] + spart[128 + tid] + spart[192 + tid]) * inv;
        }
        __syncthreads();   // B6: spart/sprob safe to overwrite next iteration
    }
}

extern "C" void kernel_launch(void* const* d_in, const int* in_sizes, int n_in,
                              void* d_out, int out_size, void* d_ws, size_t ws_size,
                              hipStream_t stream) {
    const float* query = (const float*)d_in[0];
    const float* key   = (const float*)d_in[1];
    const float* value = (const float*)d_in[2];
    const int*   mask  = (const int*)d_in[3];
    const float* W1    = (const float*)d_in[4];
    const float* b1    = (const float*)d_in[5];
    const float* a1    = (const float*)d_in[6];
    const float* W2    = (const float*)d_in[7];
    const float* b2    = (const float*)d_in[8];
    const float* a2    = (const float*)d_in[9];
    const float* Wo    = (const float*)d_in[10];
    const float* bo    = (const float*)d_in[11];
    float* out = (float*)d_out;

    float* qW      = (float*)d_ws;                       // B*H1 f32
    float* W1kG    = qW + (size_t)B_SZ * H1;             // 5120 f32
    float* W1pG    = W1kG + W1ELT;                       // 5120 f32
    _Float16* Bp2  = (_Float16*)(W1pG + W1ELT);          // 4608 halves

    qw_kernel<<<B_SZ, 128, 0, stream>>>(query, W1, b1, qW);
    prep_bp<<<(W1ELT + W2HALVES + 255) / 256, 256, 0, stream>>>(W1, W2, W1kG, W1pG, Bp2);
    fused_kernel<<<B_SZ / BPB, 256, 0, stream>>>(
        query, key, value, mask, W1kG, W1pG, Bp2, a1, b2, a2, Wo, bo, qW, out);
}

// Round 24
// 108.977 us; speedup vs baseline: 3.5871x; 3.5871x over previous
//
#include <hip/hip_runtime.h>
#include <math.h>

#define B_SZ 4096
#define N_SZ 200
#define K_SZ 64
#define H1 80
#define H2 40
#define NEG_V (-4294967295.0f)

#define NW1FRAG 10               // layer-1 W_eff frags (K=64: 2 ks x 5 ht)
#define NW2FRAG 9                // layer-2 frags (3 ks2 x 3 ht2)
#define W1ELT (NW1FRAG * 512)    // 5120 elements
#define W2HALVES (NW2FRAG * 512) // 4608 fp16 halves
#define WLDS_HALVES (W1ELT + W2HALVES)  // 9728 halves = 19,456 B

typedef _Float16 f16x8 __attribute__((ext_vector_type(8)));
typedef float f32x4 __attribute__((ext_vector_type(4)));
typedef unsigned int u32;

union H2U { _Float16 h[2]; u32 u; };
union U4F { u32 u[4]; f16x8 v; };

typedef __attribute__((address_space(3))) u32 lds_u32;
typedef const __attribute__((address_space(1))) u32 glb_u32;

__device__ __forceinline__ void gload16(const void* gp, void* lp) {
    __builtin_amdgcn_global_load_lds((glb_u32*)gp, (lds_u32*)lp, 16, 0, 0);
}

// ---------------- qW[b][h] = b1[h] + sum_i q[b][i]*(W1[i][h]+W1[128+i][h])  (exact fp32)
__global__ __launch_bounds__(128) void qw_kernel(const float* __restrict__ query,
                                                 const float* __restrict__ W1,
                                                 const float* __restrict__ b1,
                                                 float* __restrict__ qW) {
    int b = blockIdx.x;
    int tid = threadIdx.x;
    __shared__ float sq[K_SZ];
    if (tid < K_SZ) sq[tid] = query[b * K_SZ + tid];
    __syncthreads();
    if (tid < H1) {
        float acc = b1[tid];
#pragma unroll 8
        for (int i = 0; i < K_SZ; ++i)
            acc += sq[i] * (W1[i * H1 + tid] + W1[(128 + i) * H1 + tid]);
        qW[b * H1 + tid] = acc;
    }
}

// ---------------- pack weights (same layouts as R18)
__global__ __launch_bounds__(256) void prep_bp(const float* __restrict__ W1,
                                               const float* __restrict__ W2,
                                               float* __restrict__ W1kG,
                                               float* __restrict__ W1pG,
                                               _Float16* __restrict__ Bp2) {
    int idx = blockIdx.x * 256 + threadIdx.x;
    if (idx < W1ELT) {
        int j = idx & 7, lane = (idx >> 3) & 63, f = idx >> 9;
        int ks = f & 1, ht = f >> 1;
        int k = ks * 32 + (lane >> 4) * 8 + j;
        int h = ht * 16 + (lane & 15);
        W1kG[idx] = W1[(64 + k) * H1 + h] - W1[(128 + k) * H1 + h];
        W1pG[idx] = W1[(192 + k) * H1 + h];
    } else {
        int idx2 = idx - W1ELT;
        if (idx2 < W2HALVES) {
            int j = idx2 & 7, lane = (idx2 >> 3) & 63, f2 = idx2 >> 9;
            int ks2 = f2 % 3, ht2 = f2 / 3;
            int k2 = ks2 * 32 + (lane >> 4) * 8 + j;
            int m = ht2 * 16 + (lane & 15);
            float w = (k2 < H1 && m < H2) ? W2[k2 * H2 + m] : 0.0f;
            Bp2[idx2] = (_Float16)w;
        }
    }
}

// ---------------- fully fused: in-block W_eff fold, MFMA scores, softmax,
// float4 deep-issued value tail. (256,3): spill-free budget, ~4 blocks/CU.
__global__ __launch_bounds__(256, 3) void fused_kernel(
    const float* __restrict__ query, const float* __restrict__ key,
    const float* __restrict__ value, const int* __restrict__ mask,
    const float* __restrict__ W1kG, const float* __restrict__ W1pG,
    const _Float16* __restrict__ Bp2G,
    const float* __restrict__ a1, const float* __restrict__ b2,
    const float* __restrict__ a2, const float* __restrict__ Wo,
    const float* __restrict__ bo, const float* __restrict__ qW,
    float* __restrict__ out) {
    __shared__ _Float16 wlds[WLDS_HALVES];   // [0,5120): W_eff  [5120,9728): W2
    __shared__ float sq[K_SZ];
    __shared__ float sqW[H1];
    __shared__ float sa1[H1];
    __shared__ float sb2[48], sa2[48], sWo[48];
    __shared__ float sprob[256];
    __shared__ float sred[8];
    __shared__ float spart[4 * K_SZ];

    const int tid = threadIdx.x;
    const int wv = tid >> 6;
    const int l = tid & 63;
    const int l15 = l & 15;
    const int lg = l >> 4;
    const int b = blockIdx.x;
    const int p0 = b * N_SZ;
    const int NT = (wv == 0) ? 4 : 3;
    const int tb = (wv == 0) ? 0 : 1 + wv * 3;

    // ---- W2 frag DMA -> wlds[5120..]: 576 16B chunks, linear dest
    {
#pragma unroll
        for (int i = 0; i < 2; ++i) {
            int cb = i * 256 + wv * 64;
            gload16(&Bp2G[(size_t)(cb + l) * 8], (char*)&wlds[W1ELT] + (size_t)cb * 16);
        }
        if (wv == 0) {
            int cb = 512;
            gload16(&Bp2G[(size_t)(cb + l) * 8], (char*)&wlds[W1ELT] + (size_t)cb * 16);
        }
    }

    // ---- stage params
    if (tid < K_SZ) sq[tid] = query[b * K_SZ + tid];
    if (tid < H1) { sqW[tid] = qW[b * H1 + tid]; sa1[tid] = a1[tid]; }
    if (tid >= 128 && tid < 176) {
        int i = tid - 128;
        sb2[i] = (i < H2) ? b2[i] : 0.0f;
        sa2[i] = (i < H2) ? a2[i] : 0.0f;
        sWo[i] = (i < H2) ? Wo[i] : 0.0f;
    }
    float bov = bo[0];
    __syncthreads();   // A: sq visible; W2 DMA drained

    // ---- W_eff = W1k + q[k]*W1p (f32 combine, one fp16 round), 20 elts/thread
#pragma unroll
    for (int r = 0; r < 20; ++r) {
        int idx = r * 256 + tid;            // 0..5119
        int j = idx & 7, lane = (idx >> 3) & 63, f = idx >> 9;
        int k = (f & 1) * 32 + ((lane >> 4) * 8) + j;
        float w = W1kG[idx] + sq[k] * W1pG[idx];
        wlds[idx] = (_Float16)w;
    }
    __syncthreads();   // B: W_eff visible

    const int wofs = l * 8;   // lane offset within a frag (halves), linear

    // ---- key feature frags
    f16x8 Bk[4][2];
#pragma unroll
    for (int i = 0; i < 4; ++i) {
        if (i < NT) {
            int nloc = (tb + i) * 16 + l15;
            int pg = p0 + nloc;
            int pgc = (pg < B_SZ * N_SZ) ? pg : (B_SZ * N_SZ - 1);
#pragma unroll
            for (int ksp = 0; ksp < 2; ++ksp) {
                const float* kp = &key[(size_t)pgc * K_SZ + ksp * 32 + lg * 8];
                float4 k0 = *reinterpret_cast<const float4*>(kp);
                float4 k1 = *reinterpret_cast<const float4*>(kp + 4);
                f16x8 bk;
                bk[0] = (_Float16)k0.x; bk[1] = (_Float16)k0.y; bk[2] = (_Float16)k0.z; bk[3] = (_Float16)k0.w;
                bk[4] = (_Float16)k1.x; bk[5] = (_Float16)k1.y; bk[6] = (_Float16)k1.z; bk[7] = (_Float16)k1.w;
                Bk[i][ksp] = bk;
            }
        }
    }

    // ---- layer 1: D1[f][n] = sum_k W_eff[k][f] * K[k][n]   (K = 64)
    f32x4 D1[4][5];
#pragma unroll
    for (int i = 0; i < 4; ++i)
#pragma unroll
        for (int ht = 0; ht < 5; ++ht) D1[i][ht] = (f32x4){0.f, 0.f, 0.f, 0.f};
#pragma unroll
    for (int ht = 0; ht < 5; ++ht) {
#pragma unroll
        for (int ks = 0; ks < 2; ++ks) {
            f16x8 wh = *reinterpret_cast<const f16x8*>(&wlds[(ht * 2 + ks) * 512 + wofs]);
#pragma unroll
            for (int i = 0; i < 4; ++i) {
                if (i < NT) {
                    D1[i][ht] = __builtin_amdgcn_mfma_f32_16x16x32_f16(wh, Bk[i][ks], D1[i][ht], 0, 0, 0);
                }
            }
        }
    }

    // ---- epilogue 1: h1 = prelu(D1 + qW) -> packed fp16 pairs
    u32 pk[4][6][2];
#pragma unroll
    for (int i = 0; i < 4; ++i) {
        if (i < NT) {
#pragma unroll
            for (int ht = 0; ht < 5; ++ht) {
                float4 qw4 = *reinterpret_cast<const float4*>(&sqW[ht * 16 + lg * 4]);
                float4 aa4 = *reinterpret_cast<const float4*>(&sa1[ht * 16 + lg * 4]);
                float h0 = D1[i][ht][0] + qw4.x;
                float h1v = D1[i][ht][1] + qw4.y;
                float h2 = D1[i][ht][2] + qw4.z;
                float h3 = D1[i][ht][3] + qw4.w;
                h0 = (h0 > 0.f) ? h0 : h0 * aa4.x;
                h1v = (h1v > 0.f) ? h1v : h1v * aa4.y;
                h2 = (h2 > 0.f) ? h2 : h2 * aa4.z;
                h3 = (h3 > 0.f) ? h3 : h3 * aa4.w;
                H2U u0, u1;
                u0.h[0] = (_Float16)h0; u0.h[1] = (_Float16)h1v;
                u1.h[0] = (_Float16)h2; u1.h[1] = (_Float16)h3;
                pk[i][ht][0] = u0.u;
                pk[i][ht][1] = u1.u;
            }
            pk[i][5][0] = 0u; pk[i][5][1] = 0u;   // zero-pad feats 80..95
        }
    }

    // ---- layer 2: D2[m][n] = sum_k2 W2[k2][m] * h1[k2][n]
    f32x4 D2[4][3];
#pragma unroll
    for (int i = 0; i < 4; ++i)
#pragma unroll
        for (int ht = 0; ht < 3; ++ht) D2[i][ht] = (f32x4){0.f, 0.f, 0.f, 0.f};
#pragma unroll
    for (int ks2 = 0; ks2 < 3; ++ks2) {
        f16x8 B2f[4];
#pragma unroll
        for (int i = 0; i < 4; ++i) {
            if (i < NT) {
                U4F bu;
#pragma unroll
                for (int q = 0; q < 4; ++q) {
                    int src = ((lg * 2 + (q >> 1)) & 3) * 16 + l15;
                    u32 va = (u32)__shfl((int)pk[i][ks2 * 2][q & 1], src, 64);
                    u32 vb = (u32)__shfl((int)pk[i][ks2 * 2 + 1][q & 1], src, 64);
                    bu.u[q] = (lg < 2) ? va : vb;
                }
                B2f[i] = bu.v;
            }
        }
#pragma unroll
        for (int ht2 = 0; ht2 < 3; ++ht2) {
            f16x8 wh = *reinterpret_cast<const f16x8*>(&wlds[W1ELT + (ht2 * 3 + ks2) * 512 + wofs]);
#pragma unroll
            for (int i = 0; i < 4; ++i) {
                if (i < NT) {
                    D2[i][ht2] = __builtin_amdgcn_mfma_f32_16x16x32_f16(wh, B2f[i], D2[i][ht2], 0, 0, 0);
                }
            }
        }
    }

    // ---- epilogue 2 + layer 3: score(n) = bo + sum_m Wo[m]*prelu(D2[m][n]+b2[m])
#pragma unroll
    for (int i = 0; i < 4; ++i) {
        if (i < NT) {
            float psum = 0.f;
#pragma unroll
            for (int ht2 = 0; ht2 < 3; ++ht2) {
                float4 b4 = *reinterpret_cast<const float4*>(&sb2[ht2 * 16 + lg * 4]);
                float4 a4 = *reinterpret_cast<const float4*>(&sa2[ht2 * 16 + lg * 4]);
                float4 w4 = *reinterpret_cast<const float4*>(&sWo[ht2 * 16 + lg * 4]);
                float v0 = D2[i][ht2][0] + b4.x;
                float v1 = D2[i][ht2][1] + b4.y;
                float v2 = D2[i][ht2][2] + b4.z;
                float v3 = D2[i][ht2][3] + b4.w;
                v0 = (v0 > 0.f) ? v0 : v0 * a4.x;
                v1 = (v1 > 0.f) ? v1 : v1 * a4.y;
                v2 = (v2 > 0.f) ? v2 : v2 * a4.z;
                v3 = (v3 > 0.f) ? v3 : v3 * a4.w;
                psum += v0 * w4.x + v1 * w4.y + v2 * w4.z + v3 * w4.w;
            }
            psum += __shfl_xor(psum, 16);
            psum += __shfl_xor(psum, 32);
            if (lg == 0) {
                int nloc = (tb + i) * 16 + l15;
                float sv;
                if (nloc < N_SZ) sv = (mask[p0 + nloc] == 0) ? NEG_V : (psum + bov);
                else sv = -INFINITY;
                sprob[nloc] = sv;
            }
        }
    }
    __syncthreads();

    // ---- softmax over the 208 staged scores (pads are -inf)
    float s = (tid < 208) ? sprob[tid] : -INFINITY;
    float m = s;
#pragma unroll
    for (int off = 32; off >= 1; off >>= 1) m = fmaxf(m, __shfl_xor(m, off));
    if ((tid & 63) == 0) sred[tid >> 6] = m;
    __syncthreads();
    m = fmaxf(fmaxf(sred[0], sred[1]), fmaxf(sred[2], sred[3]));

    float e = (tid < 208) ? expf(s - m) : 0.0f;
    sprob[tid] = e;
    float t = e;
#pragma unroll
    for (int off = 32; off >= 1; off >>= 1) t += __shfl_xor(t, off);
    if ((tid & 63) == 0) sred[4 + (tid >> 6)] = t;
    __syncthreads();
    float inv = 1.0f / (sred[4] + sred[5] + sred[6] + sred[7]);

    // ---- value tail: float4 loads, all 13 issued before use.
    {
        const int n0 = wv * 50;
        const int g = lg;
        const int kc = l15 * 4;
        float4 vr[13];
#pragma unroll
        for (int q = 0; q < 13; ++q) {
            int sub = q * 4 + g;
            int row = n0 + ((sub < 50) ? sub : 49);
            vr[q] = *reinterpret_cast<const float4*>(
                &value[((size_t)p0 + row) * K_SZ + kc]);
        }
        f32x4 vacc = (f32x4){0.f, 0.f, 0.f, 0.f};
#pragma unroll
        for (int q = 0; q < 13; ++q) {
            int sub = q * 4 + g;
            float w = (sub < 50) ? sprob[n0 + sub] : 0.0f;
            vacc[0] += w * vr[q].x;
            vacc[1] += w * vr[q].y;
            vacc[2] += w * vr[q].z;
            vacc[3] += w * vr[q].w;
        }
#pragma unroll
        for (int e2 = 0; e2 < 4; ++e2) {
            vacc[e2] += __shfl_xor(vacc[e2], 16);
            vacc[e2] += __shfl_xor(vacc[e2], 32);
        }
        if (lg == 0) {
            float4 vout = {vacc[0], vacc[1], vacc[2], vacc[3]};
            *reinterpret_cast<float4*>(&spart[wv * K_SZ + kc]) = vout;
        }
    }
    __syncthreads();
    if (tid < K_SZ) {
        out[b * K_SZ + tid] =
            (spart[tid] + spart[64 + tid] + spart[128 + tid] + spart[192 + tid]) * inv;
    }
}

extern "C" void kernel_launch(void* const* d_in, const int* in_sizes, int n_in,
                              void* d_out, int out_size, void* d_ws, size_t ws_size,
                              hipStream_t stream) {
    const float* query = (const float*)d_in[0];
    const float* key   = (const float*)d_in[1];
    const float* value = (const float*)d_in[2];
    const int*   mask  = (const int*)d_in[3];
    const float* W1    = (const float*)d_in[4];
    const float* b1    = (const float*)d_in[5];
    const float* a1    = (const float*)d_in[6];
    const float* W2    = (const float*)d_in[7];
    const float* b2    = (const float*)d_in[8];
    const float* a2    = (const float*)d_in[9];
    const float* Wo    = (const float*)d_in[10];
    const float* bo    = (const float*)d_in[11];
    float* out = (float*)d_out;

    float* qW      = (float*)d_ws;                       // B*H1 f32
    float* W1kG    = qW + (size_t)B_SZ * H1;             // 5120 f32
    float* W1pG    = W1kG + W1ELT;                       // 5120 f32
    _Float16* Bp2  = (_Float16*)(W1pG + W1ELT);          // 4608 halves

    qw_kernel<<<B_SZ, 128, 0, stream>>>(query, W1, b1, qW);
    prep_bp<<<(W1ELT + W2HALVES + 255) / 256, 256, 0, stream>>>(W1, W2, W1kG, W1pG, Bp2);
    fused_kernel<<<B_SZ, 256, 0, stream>>>(
        query, key, value, mask, W1kG, W1pG, Bp2, a1, b2, a2, Wo, bo, qW, out);
}

// Round 25
// 106.267 us; speedup vs baseline: 3.6786x; 1.0255x over previous
//
#include <hip/hip_runtime.h>
#include <math.h>

#define B_SZ 4096
#define N_SZ 200
#define K_SZ 64
#define H1 80
#define H2 40
#define NEG_V (-4294967295.0f)

#define NW1FRAG 10               // layer-1 W_eff frags (K=64: 2 ks x 5 ht)
#define NW2FRAG 9                // layer-2 frags (3 ks2 x 3 ht2)
#define W1ELT (NW1FRAG * 512)    // 5120 elements
#define W2HALVES (NW2FRAG * 512) // 4608 fp16 halves
#define WLDS_HALVES (W1ELT + W2HALVES)  // 9728 halves = 19,456 B

typedef _Float16 f16x8 __attribute__((ext_vector_type(8)));
typedef float f32x4 __attribute__((ext_vector_type(4)));
typedef unsigned int u32;

union H2U { _Float16 h[2]; u32 u; };
union U4F { u32 u[4]; f16x8 v; };

typedef __attribute__((address_space(3))) u32 lds_u32;
typedef const __attribute__((address_space(1))) u32 glb_u32;

__device__ __forceinline__ void gload16(const void* gp, void* lp) {
    __builtin_amdgcn_global_load_lds((glb_u32*)gp, (lds_u32*)lp, 16, 0, 0);
}

// ---------------- qW[b][h] = b1[h] + sum_i q[b][i]*(W1[i][h]+W1[128+i][h])  (exact fp32)
__global__ __launch_bounds__(128) void qw_kernel(const float* __restrict__ query,
                                                 const float* __restrict__ W1,
                                                 const float* __restrict__ b1,
                                                 float* __restrict__ qW) {
    int b = blockIdx.x;
    int tid = threadIdx.x;
    __shared__ float sq[K_SZ];
    if (tid < K_SZ) sq[tid] = query[b * K_SZ + tid];
    __syncthreads();
    if (tid < H1) {
        float acc = b1[tid];
#pragma unroll 8
        for (int i = 0; i < K_SZ; ++i)
            acc += sq[i] * (W1[i * H1 + tid] + W1[(128 + i) * H1 + tid]);
        qW[b * H1 + tid] = acc;
    }
}

// ---------------- pack weights (same layouts as R18)
__global__ __launch_bounds__(256) void prep_bp(const float* __restrict__ W1,
                                               const float* __restrict__ W2,
                                               float* __restrict__ W1kG,
                                               float* __restrict__ W1pG,
                                               _Float16* __restrict__ Bp2) {
    int idx = blockIdx.x * 256 + threadIdx.x;
    if (idx < W1ELT) {
        int j = idx & 7, lane = (idx >> 3) & 63, f = idx >> 9;
        int ks = f & 1, ht = f >> 1;
        int k = ks * 32 + (lane >> 4) * 8 + j;
        int h = ht * 16 + (lane & 15);
        W1kG[idx] = W1[(64 + k) * H1 + h] - W1[(128 + k) * H1 + h];
        W1pG[idx] = W1[(192 + k) * H1 + h];
    } else {
        int idx2 = idx - W1ELT;
        if (idx2 < W2HALVES) {
            int j = idx2 & 7, lane = (idx2 >> 3) & 63, f2 = idx2 >> 9;
            int ks2 = f2 % 3, ht2 = f2 / 3;
            int k2 = ks2 * 32 + (lane >> 4) * 8 + j;
            int m = ht2 * 16 + (lane & 15);
            float w = (k2 < H1 && m < H2) ? W2[k2 * H2 + m] : 0.0f;
            Bp2[idx2] = (_Float16)w;
        }
    }
}

// ---------------- fully fused: in-block W_eff fold, MFMA scores, softmax,
// value tail with loads ISSUED after layer-2 (low-pressure window) and
// consumed after softmax — the pre-softmax barrier drain hides them.
__global__ __launch_bounds__(256, 3) void fused_kernel(
    const float* __restrict__ query, const float* __restrict__ key,
    const float* __restrict__ value, const int* __restrict__ mask,
    const float* __restrict__ W1kG, const float* __restrict__ W1pG,
    const _Float16* __restrict__ Bp2G,
    const float* __restrict__ a1, const float* __restrict__ b2,
    const float* __restrict__ a2, const float* __restrict__ Wo,
    const float* __restrict__ bo, const float* __restrict__ qW,
    float* __restrict__ out) {
    __shared__ _Float16 wlds[WLDS_HALVES];   // [0,5120): W_eff  [5120,9728): W2
    __shared__ float sq[K_SZ];
    __shared__ float sqW[H1];
    __shared__ float sa1[H1];
    __shared__ float sb2[48], sa2[48], sWo[48];
    __shared__ float sprob[256];
    __shared__ float sred[8];
    __shared__ float spart[4 * K_SZ];

    const int tid = threadIdx.x;
    const int wv = tid >> 6;
    const int l = tid & 63;
    const int l15 = l & 15;
    const int lg = l >> 4;
    const int b = blockIdx.x;
    const int p0 = b * N_SZ;
    const int NT = (wv == 0) ? 4 : 3;
    const int tb = (wv == 0) ? 0 : 1 + wv * 3;

    // ---- W2 frag DMA -> wlds[5120..]: 576 16B chunks, linear dest
    {
#pragma unroll
        for (int i = 0; i < 2; ++i) {
            int cb = i * 256 + wv * 64;
            gload16(&Bp2G[(size_t)(cb + l) * 8], (char*)&wlds[W1ELT] + (size_t)cb * 16);
        }
        if (wv == 0) {
            int cb = 512;
            gload16(&Bp2G[(size_t)(cb + l) * 8], (char*)&wlds[W1ELT] + (size_t)cb * 16);
        }
    }

    // ---- stage params
    if (tid < K_SZ) sq[tid] = query[b * K_SZ + tid];
    if (tid < H1) { sqW[tid] = qW[b * H1 + tid]; sa1[tid] = a1[tid]; }
    if (tid >= 128 && tid < 176) {
        int i = tid - 128;
        sb2[i] = (i < H2) ? b2[i] : 0.0f;
        sa2[i] = (i < H2) ? a2[i] : 0.0f;
        sWo[i] = (i < H2) ? Wo[i] : 0.0f;
    }
    float bov = bo[0];
    __syncthreads();   // A: sq visible; W2 DMA drained

    // ---- W_eff = W1k + q[k]*W1p (f32 combine, one fp16 round), 20 elts/thread
#pragma unroll
    for (int r = 0; r < 20; ++r) {
        int idx = r * 256 + tid;            // 0..5119
        int j = idx & 7, lane = (idx >> 3) & 63, f = idx >> 9;
        int k = (f & 1) * 32 + ((lane >> 4) * 8) + j;
        float w = W1kG[idx] + sq[k] * W1pG[idx];
        wlds[idx] = (_Float16)w;
    }
    __syncthreads();   // B: W_eff visible

    const int wofs = l * 8;   // lane offset within a frag (halves), linear

    // ---- key feature frags
    f16x8 Bk[4][2];
#pragma unroll
    for (int i = 0; i < 4; ++i) {
        if (i < NT) {
            int nloc = (tb + i) * 16 + l15;
            int pg = p0 + nloc;
            int pgc = (pg < B_SZ * N_SZ) ? pg : (B_SZ * N_SZ - 1);
#pragma unroll
            for (int ksp = 0; ksp < 2; ++ksp) {
                const float* kp = &key[(size_t)pgc * K_SZ + ksp * 32 + lg * 8];
                float4 k0 = *reinterpret_cast<const float4*>(kp);
                float4 k1 = *reinterpret_cast<const float4*>(kp + 4);
                f16x8 bk;
                bk[0] = (_Float16)k0.x; bk[1] = (_Float16)k0.y; bk[2] = (_Float16)k0.z; bk[3] = (_Float16)k0.w;
                bk[4] = (_Float16)k1.x; bk[5] = (_Float16)k1.y; bk[6] = (_Float16)k1.z; bk[7] = (_Float16)k1.w;
                Bk[i][ksp] = bk;
            }
        }
    }

    // ---- layer 1: D1[f][n] = sum_k W_eff[k][f] * K[k][n]   (K = 64)
    f32x4 D1[4][5];
#pragma unroll
    for (int i = 0; i < 4; ++i)
#pragma unroll
        for (int ht = 0; ht < 5; ++ht) D1[i][ht] = (f32x4){0.f, 0.f, 0.f, 0.f};
#pragma unroll
    for (int ht = 0; ht < 5; ++ht) {
#pragma unroll
        for (int ks = 0; ks < 2; ++ks) {
            f16x8 wh = *reinterpret_cast<const f16x8*>(&wlds[(ht * 2 + ks) * 512 + wofs]);
#pragma unroll
            for (int i = 0; i < 4; ++i) {
                if (i < NT) {
                    D1[i][ht] = __builtin_amdgcn_mfma_f32_16x16x32_f16(wh, Bk[i][ks], D1[i][ht], 0, 0, 0);
                }
            }
        }
    }

    // ---- epilogue 1: h1 = prelu(D1 + qW) -> packed fp16 pairs
    u32 pk[4][6][2];
#pragma unroll
    for (int i = 0; i < 4; ++i) {
        if (i < NT) {
#pragma unroll
            for (int ht = 0; ht < 5; ++ht) {
                float4 qw4 = *reinterpret_cast<const float4*>(&sqW[ht * 16 + lg * 4]);
                float4 aa4 = *reinterpret_cast<const float4*>(&sa1[ht * 16 + lg * 4]);
                float h0 = D1[i][ht][0] + qw4.x;
                float h1v = D1[i][ht][1] + qw4.y;
                float h2 = D1[i][ht][2] + qw4.z;
                float h3 = D1[i][ht][3] + qw4.w;
                h0 = (h0 > 0.f) ? h0 : h0 * aa4.x;
                h1v = (h1v > 0.f) ? h1v : h1v * aa4.y;
                h2 = (h2 > 0.f) ? h2 : h2 * aa4.z;
                h3 = (h3 > 0.f) ? h3 : h3 * aa4.w;
                H2U u0, u1;
                u0.h[0] = (_Float16)h0; u0.h[1] = (_Float16)h1v;
                u1.h[0] = (_Float16)h2; u1.h[1] = (_Float16)h3;
                pk[i][ht][0] = u0.u;
                pk[i][ht][1] = u1.u;
            }
            pk[i][5][0] = 0u; pk[i][5][1] = 0u;   // zero-pad feats 80..95
        }
    }

    // ---- layer 2: D2[m][n] = sum_k2 W2[k2][m] * h1[k2][n]
    f32x4 D2[4][3];
#pragma unroll
    for (int i = 0; i < 4; ++i)
#pragma unroll
        for (int ht = 0; ht < 3; ++ht) D2[i][ht] = (f32x4){0.f, 0.f, 0.f, 0.f};
#pragma unroll
    for (int ks2 = 0; ks2 < 3; ++ks2) {
        f16x8 B2f[4];
#pragma unroll
        for (int i = 0; i < 4; ++i) {
            if (i < NT) {
                U4F bu;
#pragma unroll
                for (int q = 0; q < 4; ++q) {
                    int src = ((lg * 2 + (q >> 1)) & 3) * 16 + l15;
                    u32 va = (u32)__shfl((int)pk[i][ks2 * 2][q & 1], src, 64);
                    u32 vb = (u32)__shfl((int)pk[i][ks2 * 2 + 1][q & 1], src, 64);
                    bu.u[q] = (lg < 2) ? va : vb;
                }
                B2f[i] = bu.v;
            }
        }
#pragma unroll
        for (int ht2 = 0; ht2 < 3; ++ht2) {
            f16x8 wh = *reinterpret_cast<const f16x8*>(&wlds[W1ELT + (ht2 * 3 + ks2) * 512 + wofs]);
#pragma unroll
            for (int i = 0; i < 4; ++i) {
                if (i < NT) {
                    D2[i][ht2] = __builtin_amdgcn_mfma_f32_16x16x32_f16(wh, B2f[i], D2[i][ht2], 0, 0, 0);
                }
            }
        }
    }

    // ---- value PREFETCH: issue in the low-pressure window (pk/B2f dead);
    // loads retire under epilogue-2 + score stores + softmax barriers.
    const int n0v = wv * 50;
    const int kcv = l15 * 4;
    float4 vr[13];
#pragma unroll
    for (int q = 0; q < 13; ++q) {
        int sub = q * 4 + lg;
        int row = n0v + ((sub < 50) ? sub : 49);
        vr[q] = *reinterpret_cast<const float4*>(
            &value[((size_t)p0 + row) * K_SZ + kcv]);
    }

    // ---- epilogue 2 + layer 3: score(n) = bo + sum_m Wo[m]*prelu(D2[m][n]+b2[m])
#pragma unroll
    for (int i = 0; i < 4; ++i) {
        if (i < NT) {
            float psum = 0.f;
#pragma unroll
            for (int ht2 = 0; ht2 < 3; ++ht2) {
                float4 b4 = *reinterpret_cast<const float4*>(&sb2[ht2 * 16 + lg * 4]);
                float4 a4 = *reinterpret_cast<const float4*>(&sa2[ht2 * 16 + lg * 4]);
                float4 w4 = *reinterpret_cast<const float4*>(&sWo[ht2 * 16 + lg * 4]);
                float v0 = D2[i][ht2][0] + b4.x;
                float v1 = D2[i][ht2][1] + b4.y;
                float v2 = D2[i][ht2][2] + b4.z;
                float v3 = D2[i][ht2][3] + b4.w;
                v0 = (v0 > 0.f) ? v0 : v0 * a4.x;
                v1 = (v1 > 0.f) ? v1 : v1 * a4.y;
                v2 = (v2 > 0.f) ? v2 : v2 * a4.z;
                v3 = (v3 > 0.f) ? v3 : v3 * a4.w;
                psum += v0 * w4.x + v1 * w4.y + v2 * w4.z + v3 * w4.w;
            }
            psum += __shfl_xor(psum, 16);
            psum += __shfl_xor(psum, 32);
            if (lg == 0) {
                int nloc = (tb + i) * 16 + l15;
                float sv;
                if (nloc < N_SZ) sv = (mask[p0 + nloc] == 0) ? NEG_V : (psum + bov);
                else sv = -INFINITY;
                sprob[nloc] = sv;
            }
        }
    }
    __syncthreads();   // C: scores staged; value prefetch drained here (hidden)

    // ---- softmax over the 208 staged scores (pads are -inf)
    float s = (tid < 208) ? sprob[tid] : -INFINITY;
    float m = s;
#pragma unroll
    for (int off = 32; off >= 1; off >>= 1) m = fmaxf(m, __shfl_xor(m, off));
    if ((tid & 63) == 0) sred[tid >> 6] = m;
    __syncthreads();
    m = fmaxf(fmaxf(sred[0], sred[1]), fmaxf(sred[2], sred[3]));

    float e = (tid < 208) ? expf(s - m) : 0.0f;
    sprob[tid] = e;
    float t = e;
#pragma unroll
    for (int off = 32; off >= 1; off >>= 1) t += __shfl_xor(t, off);
    if ((tid & 63) == 0) sred[4 + (tid >> 6)] = t;
    __syncthreads();
    float inv = 1.0f / (sred[4] + sred[5] + sred[6] + sred[7]);

    // ---- value tail from prefetched registers
    {
        f32x4 vacc = (f32x4){0.f, 0.f, 0.f, 0.f};
#pragma unroll
        for (int q = 0; q < 13; ++q) {
            int sub = q * 4 + lg;
            float w = (sub < 50) ? sprob[n0v + sub] : 0.0f;
            vacc[0] += w * vr[q].x;
            vacc[1] += w * vr[q].y;
            vacc[2] += w * vr[q].z;
            vacc[3] += w * vr[q].w;
        }
#pragma unroll
        for (int e2 = 0; e2 < 4; ++e2) {
            vacc[e2] += __shfl_xor(vacc[e2], 16);
            vacc[e2] += __shfl_xor(vacc[e2], 32);
        }
        if (lg == 0) {
            float4 vout = {vacc[0], vacc[1], vacc[2], vacc[3]};
            *reinterpret_cast<float4*>(&spart[wv * K_SZ + kcv]) = vout;
        }
    }
    __syncthreads();
    if (tid < K_SZ) {
        out[b * K_SZ + tid] =
            (spart[tid] + spart[64 + tid] + spart[128 + tid] + spart[192 + tid]) * inv;
    }
}

extern "C" void kernel_launch(void* const* d_in, const int* in_sizes, int n_in,
                              void* d_out, int out_size, void* d_ws, size_t ws_size,
                              hipStream_t stream) {
    const float* query = (const float*)d_in[0];
    const float* key   = (const float*)d_in[1];
    const float* value = (const float*)d_in[2];
    const int*   mask  = (const int*)d_in[3];
    const float* W1    = (const float*)d_in[4];
    const float* b1    = (const float*)d_in[5];
    const float* a1    = (const float*)d_in[6];
    const float* W2    = (const float*)d_in[7];
    const float* b2    = (const float*)d_in[8];
    const float* a2    = (const float*)d_in[9];
    const float* Wo    = (const float*)d_in[10];
    const float* bo    = (const float*)d_in[11];
    float* out = (float*)d_out;

    float* qW      = (float*)d_ws;                       // B*H1 f32
    float* W1kG    = qW + (size_t)B_SZ * H1;             // 5120 f32
    float* W1pG    = W1kG + W1ELT;                       // 5120 f32
    _Float16* Bp2  = (_Float16*)(W1pG + W1ELT);          // 4608 halves

    qw_kernel<<<B_SZ, 128, 0, stream>>>(query, W1, b1, qW);
    prep_bp<<<(W1ELT + W2HALVES + 255) / 256, 256, 0, stream>>>(W1, W2, W1kG, W1pG, Bp2);
    fused_kernel<<<B_SZ, 256, 0, stream>>>(
        query, key, value, mask, W1kG, W1pG, Bp2, a1, b2, a2, Wo, bo, qW, out);
}